// Round 1
// 723.501 us; speedup vs baseline: 1.0129x; 1.0129x over previous
//
#include <hip/hip_runtime.h>

#define B_ 128
#define S_ 4096
#define D_ 256
#define U_ 128
#define CR_ 64          // rows per chunk
#define NSL_ 4          // sequence slices per batch
#define SLR_ 1024       // rows per slice
#define NCH_ 16         // chunks per block (1024 / 64)
#define PITCH 264       // padded LDS pitch in halfs

typedef _Float16 half8 __attribute__((ext_vector_type(8)));
typedef _Float16 half4_t __attribute__((ext_vector_type(4)));
typedef float f32x4 __attribute__((ext_vector_type(4)));

// ---------------- setup kernels ----------------

__global__ void qp_kernel(const float* __restrict__ query,
                          const float* __restrict__ W1,
                          const float* __restrict__ b1,
                          const float* __restrict__ b2,
                          float* __restrict__ qp) {
  const int idx = blockIdx.x * 256 + threadIdx.x;   // 16384 = B_*U_
  const int b = idx >> 7;
  const int u = idx & 127;
  float acc = b1[u] + b2[u];              // fold b2 into qp
  const float* q = query + b * D_;
  #pragma unroll 8
  for (int d = 0; d < D_; ++d) acc += q[d] * W1[d * U_ + u];
  qp[idx] = acc;
}

__global__ void w2t_kernel(const float* __restrict__ W2,
                           _Float16* __restrict__ w2t) {
  const int idx = blockIdx.x * 256 + threadIdx.x;   // 32768 = U_*D_
  const int u = idx >> 8;
  const int d = idx & 255;
  w2t[idx] = (_Float16)W2[d * U_ + u];              // w2t[u][d]
}

// ---------------- main fused persistent kernel ----------------
// grid 512 blocks x 512 threads; block = (b, slice): 16 chunks of 64 rows.
// W2^T lives in registers (wave w owns u in [w*16, w*16+16)); values double-
// buffered in LDS f16; per-wave redundant online softmax (no serial wave);
// 2 barriers per chunk.

__global__ __launch_bounds__(512, 4)
void main_kernel(const float* __restrict__ values,
                 const float* __restrict__ qp,
                 const _Float16* __restrict__ w2t,
                 const float* __restrict__ Wv,
                 const float* __restrict__ bv,
                 float* __restrict__ scores,
                 float* __restrict__ part) {
  // Alds[2][CR_][PITCH] halfs; ctxpart aliases buffer 0 after the loop.
  __shared__ __align__(16) char smem[2 * CR_ * PITCH * 2];
  _Float16 (*Alds)[CR_][PITCH] = (_Float16 (*)[CR_][PITCH])smem;
  __shared__ float sb[8][CR_];

  const int t = threadIdx.x;
  const int b = blockIdx.x >> 2;
  const int sl = blockIdx.x & 3;
  const int lane = t & 63;
  const int wave = t >> 6;
  const int lm = lane & 15;
  const int lq = lane >> 4;
  const int lk = lq * 8;

  const f32x4* __restrict__ vbase =
      (const f32x4*)(values + ((size_t)b * S_ + (size_t)sl * SLR_) * D_);

  // ---- prologue: stage chunk 0 + load B fragments / qp / wv ----
  {
    f32x4 v[8];
    #pragma unroll
    for (int i = 0; i < 8; ++i) v[i] = vbase[t + i * 512];
    #pragma unroll
    for (int i = 0; i < 8; ++i) {
      const int idx = t + i * 512;        // 0..4095 f32x4
      const int row = idx >> 6;
      const int d4 = idx & 63;
      half4_t h;
      h[0] = (_Float16)v[i][0]; h[1] = (_Float16)v[i][1];
      h[2] = (_Float16)v[i][2]; h[3] = (_Float16)v[i][3];
      *(half4_t*)&Alds[0][row][d4 * 4] = h;
    }
  }

  // W2^T fragments: lane holds u = wave*16 + lm, k-slice kk*32 + lq*8
  half8 breg[8];
  {
    const half8* __restrict__ wp =
        (const half8*)(w2t + (size_t)(wave * 16 + lm) * D_);
    #pragma unroll
    for (int kk = 0; kk < 8; ++kk) breg[kk] = wp[kk * 4 + lq];
  }
  // qp / Wv for u = wave*16 + lq*4 + r  (r = acc reg index)
  const int ub = wave * 16 + lq * 4;
  const f32x4 qv  = *(const f32x4*)(qp + (size_t)b * U_ + ub);
  const f32x4 wv4 = *(const f32x4*)(Wv + ub);
  const float bvv = bv[0];

  __syncthreads();

  float M = -INFINITY, L = 0.0f;
  float cacc[8];
  #pragma unroll
  for (int j = 0; j < 8; ++j) cacc[j] = 0.0f;
  const int rg = t >> 5;                  // 0..15
  const int v8 = (t & 31) * 8;

  for (int c = 0; c < NCH_; ++c) {
    const int cur = c & 1;

    // ---- prefetch next chunk into registers ----
    f32x4 pf[8];
    if (c + 1 < NCH_) {
      const f32x4* __restrict__ src = vbase + (size_t)(c + 1) * (CR_ * 64);
      #pragma unroll
      for (int i = 0; i < 8; ++i) pf[i] = src[t + i * 512];
    }

    // ---- GEMM: C[u][row] for this wave's 16 u x 64 rows ----
    f32x4 acc[4];
    const f32x4 zero = {0.0f, 0.0f, 0.0f, 0.0f};
    #pragma unroll
    for (int rt = 0; rt < 4; ++rt) acc[rt] = zero;
    #pragma unroll
    for (int kk = 0; kk < 8; ++kk) {
      #pragma unroll
      for (int rt = 0; rt < 4; ++rt) {
        half8 af = *(const half8*)&Alds[cur][rt * 16 + lm][kk * 32 + lk];
        acc[rt] = __builtin_amdgcn_mfma_f32_16x16x32_f16(breg[kk], af, acc[rt], 0, 0, 0);
      }
    }

    // ---- epilogue: tanh + Wv, reduce over this wave's 16 u (2 shfl) ----
    #pragma unroll
    for (int rt = 0; rt < 4; ++rt) {
      float rs = 0.0f;
      #pragma unroll
      for (int r = 0; r < 4; ++r) {
        const float x = acc[rt][r] + qv[r];
        const float e = __expf(2.0f * x);
        rs += (1.0f - 2.0f / (e + 1.0f)) * wv4[r];   // tanh(x)*wv
      }
      rs += __shfl_xor(rs, 16);
      rs += __shfl_xor(rs, 32);
      if (lq == 0) sb[wave][rt * 16 + lm] = rs;
    }
    __syncthreads();                       // S1: sb ready

    // ---- per-wave redundant chunk softmax + online update ----
    float sc = bvv;
    #pragma unroll
    for (int w = 0; w < 8; ++w) sc += sb[w][lane];
    if (wave == 0)
      scores[(size_t)b * S_ + (size_t)sl * SLR_ + c * CR_ + lane] = sc;
    float mv = sc;
    mv = fmaxf(mv, __shfl_xor(mv, 1));
    mv = fmaxf(mv, __shfl_xor(mv, 2));
    mv = fmaxf(mv, __shfl_xor(mv, 4));
    mv = fmaxf(mv, __shfl_xor(mv, 8));
    mv = fmaxf(mv, __shfl_xor(mv, 16));
    mv = fmaxf(mv, __shfl_xor(mv, 32));
    const float m_new = fmaxf(M, mv);
    const float p = __expf(sc - m_new);    // lane holds p for row=lane
    float lv = p;
    lv += __shfl_xor(lv, 1);
    lv += __shfl_xor(lv, 2);
    lv += __shfl_xor(lv, 4);
    lv += __shfl_xor(lv, 8);
    lv += __shfl_xor(lv, 16);
    lv += __shfl_xor(lv, 32);
    const float alpha = __expf(M - m_new);
    M = m_new;
    L = L * alpha + lv;

    // ---- context accumulate from LDS chunk (p via shfl, no barrier) ----
    #pragma unroll
    for (int j = 0; j < 8; ++j) cacc[j] *= alpha;
    #pragma unroll
    for (int r = 0; r < 4; ++r) {
      const int row = rg * 4 + r;
      const float pr = __shfl(p, row);
      half8 hv = *(const half8*)&Alds[cur][row][v8];
      #pragma unroll
      for (int j = 0; j < 8; ++j) cacc[j] += pr * (float)hv[j];
    }

    // ---- convert prefetched regs -> other LDS buffer ----
    if (c + 1 < NCH_) {
      #pragma unroll
      for (int i = 0; i < 8; ++i) {
        const int idx = t + i * 512;
        const int row = idx >> 6;
        const int d4 = idx & 63;
        half4_t h;
        h[0] = (_Float16)pf[i][0]; h[1] = (_Float16)pf[i][1];
        h[2] = (_Float16)pf[i][2]; h[3] = (_Float16)pf[i][3];
        *(half4_t*)&Alds[cur ^ 1][row][d4 * 4] = h;
      }
    }
    __syncthreads();                       // S2: next buffer ready
  }

  // ---- block epilogue: reduce context partials (ctxpart aliases Alds[0]) ----
  float (*ctxpart)[D_] = (float (*)[D_])smem;
  #pragma unroll
  for (int j = 0; j < 8; ++j) ctxpart[rg][v8 + j] = cacc[j];
  __syncthreads();
  if (t < D_) {
    float s = 0.0f;
    #pragma unroll
    for (int g = 0; g < 16; ++g) s += ctxpart[g][t];
    const size_t base = (size_t)blockIdx.x * 258;
    part[base + 2 + t] = s;
    if (t == 0) { part[base] = M; part[base + 1] = L; }
  }
}

// ---------------- combine 4 slices -> context, final m/l ----------------

__global__ void combine_kernel(const float* __restrict__ part,
                               float* __restrict__ ml,
                               float* __restrict__ out_ctx) {
  const int b = blockIdx.x;
  const int t = threadIdx.x;   // 256 = D_
  const size_t p0 = (size_t)b * 4 * 258;
  const float m0 = part[p0],           l0 = part[p0 + 1];
  const float m1 = part[p0 + 258],     l1 = part[p0 + 258 + 1];
  const float m2 = part[p0 + 516],     l2 = part[p0 + 516 + 1];
  const float m3 = part[p0 + 774],     l3 = part[p0 + 774 + 1];
  const float Mf = fmaxf(fmaxf(m0, m1), fmaxf(m2, m3));
  const float s0 = __expf(m0 - Mf);
  const float s1 = __expf(m1 - Mf);
  const float s2 = __expf(m2 - Mf);
  const float s3 = __expf(m3 - Mf);
  const float Lf = l0 * s0 + l1 * s1 + l2 * s2 + l3 * s3;
  out_ctx[b * D_ + t] = (part[p0 + 2 + t] * s0 + part[p0 + 258 + 2 + t] * s1 +
                         part[p0 + 516 + 2 + t] * s2 + part[p0 + 774 + 2 + t] * s3) / Lf;
  if (t == 0) { ml[b * 2] = Mf; ml[b * 2 + 1] = Lf; }
}

// ---------------- attention weights output ----------------

__global__ void weights_kernel(const float* __restrict__ scores,
                               const float* __restrict__ ml,
                               float* __restrict__ out_w) {
  const int idx = blockIdx.x * 256 + threadIdx.x;   // 524288
  const int b = idx >> 12;
  const float M = ml[b * 2];
  const float L = ml[b * 2 + 1];
  out_w[idx] = __expf(scores[idx] - M) / L;
}

// ---------------- launch ----------------

extern "C" void kernel_launch(void* const* d_in, const int* in_sizes, int n_in,
                              void* d_out, int out_size, void* d_ws, size_t ws_size,
                              hipStream_t stream) {
  const float* query  = (const float*)d_in[0];
  const float* values = (const float*)d_in[1];
  const float* W1     = (const float*)d_in[2];
  const float* b1     = (const float*)d_in[3];
  const float* W2     = (const float*)d_in[4];
  const float* b2     = (const float*)d_in[5];
  const float* Wv     = (const float*)d_in[6];
  const float* bv     = (const float*)d_in[7];

  float* out_ctx = (float*)d_out;            // [128][256]
  float* out_w   = out_ctx + B_ * D_;        // [128][4096]

  char* ws = (char*)d_ws;
  float*     qp     = (float*)ws;                                  // 64 KB
  _Float16*  w2t    = (_Float16*)(ws + 65536);                     // 64 KB
  float*     scores = (float*)(ws + 131072);                       // 2 MB
  float*     part   = (float*)(ws + 131072 + 2097152);             // 512*258*4 = 528384 B
  float*     ml     = (float*)(ws + 131072 + 2097152 + 528384);    // 1 KB

  qp_kernel<<<dim3(64), dim3(256), 0, stream>>>(query, W1, b1, b2, qp);
  w2t_kernel<<<dim3(128), dim3(256), 0, stream>>>(W2, w2t);
  main_kernel<<<dim3(B_ * NSL_), dim3(512), 0, stream>>>(values, qp, w2t, Wv, bv,
                                                         scores, part);
  combine_kernel<<<dim3(B_), dim3(256), 0, stream>>>(part, ml, out_ctx);
  weights_kernel<<<dim3(B_ * S_ / 256), dim3(256), 0, stream>>>(scores, ml, out_w);
}